// Round 2
// baseline (161.549 us; speedup 1.0000x reference)
//
#include <hip/hip_runtime.h>
#include <hip/hip_bf16.h>

#define BATCH 32768
#define NF    64              // fields (K and N of the GEMM)
#define NE    12              // embedding dim
#define MB    16              // batch rows per tile
#define MROWS (MB*NE)         // 192 M-rows per tile
#define LSTR  68              // LDS f32 row stride (64 + 4 pad, b128-aligned)
#define SSTR  72              // S-tile ushort row stride (64+8: de-conflicts frag reads)
#define NTILE (BATCH/MB)      // 2048
#define GRID  512
#define TPB   (NTILE/GRID)    // 4 tiles per block

typedef __attribute__((ext_vector_type(8))) short short8;   // 8 bf16 = 4 VGPR
typedef __attribute__((ext_vector_type(4))) float float4v;

__device__ __forceinline__ short bfb(float v) {
    union { __hip_bfloat16 h; short s; } u;
    u.h = __float2bfloat16(v);
    return u.s;
}

// Fully fused: each block derives its own S fragments from V (one-time, S
// staged in LDS space that Xs reuses afterwards), then streams 4 x-tiles.
// No prep kernel, no workspace -> one dispatch per iteration.
__global__ __launch_bounds__(256, 2) void ffm_fused(
    const float* __restrict__ x,
    const float* __restrict__ W,
    const float* __restrict__ bvec,
    const float* __restrict__ V,
    float* __restrict__ out)
{
    __shared__ __align__(16) float Xs[MROWS * LSTR];   // 51 KB, [(b,e)][i] fp32
    __shared__ float red[MROWS];
    __shared__ float Wl[NF * NE];                      // 3 KB, W verbatim

    // S hi/lo staging aliases the head of Xs (dead before first x scatter).
    unsigned short* Sh = (unsigned short*)Xs;          // [64][SSTR] ushort
    unsigned short* Sl = Sh + NF * SSTR;               // 9216 B offset, 16B aligned

    const int tid  = threadIdx.x;
    const int w    = tid >> 6;
    const int lane = tid & 63;
    const int l15  = lane & 15;
    const int q    = lane >> 4;

    // ---- 1. issue tile-0 x loads FIRST (latency overlaps the S phase)
    float4v v[12];
    {
        const float4v* xg = (const float4v*)(x + (size_t)blockIdx.x * MB * (NF * NE));
        #pragma unroll
        for (int p = 0; p < 12; ++p) v[p] = xg[p * 256 + tid];
    }

    const float bias = bvec[0];

    // ---- 2. stage W into LDS (read once per tile in the acc-init)
    #pragma unroll
    for (int k = 0; k < 3; ++k) Wl[k * 256 + tid] = W[k * 256 + tid];

    // ---- 3. compute S^T[n][k] = 0.5*<V[k,n,:],V[n,k,:]> (0 diag), hi/lo bf16
    //         thread t: row n = t>>2, k = (t&3)*16 .. +15   (V is L2-hot: 64 KB)
    {
        const int n  = tid >> 2;
        const int kq = tid & 3;
        float sv[16];
        #pragma unroll
        for (int c = 0; c < 16; ++c) {
            const int k = kq * 16 + c;
            const float4v a = *(const float4v*)(V + (size_t)((k << 6) | n) * 4);
            const float4v b = *(const float4v*)(V + (size_t)((n << 6) | k) * 4);
            sv[c] = (n == k) ? 0.0f
                  : 0.5f * (a.x * b.x + a.y * b.y + a.z * b.z + a.w * b.w);
        }
        short8 ph0, ph1, pl0, pl1;
        #pragma unroll
        for (int j = 0; j < 8; ++j) {
            const float s0 = sv[j], s1 = sv[8 + j];
            const __hip_bfloat16 h0 = __float2bfloat16(s0);
            const __hip_bfloat16 h1 = __float2bfloat16(s1);
            ph0[j] = bfb(s0); pl0[j] = bfb(s0 - __bfloat162float(h0));
            ph1[j] = bfb(s1); pl1[j] = bfb(s1 - __bfloat162float(h1));
        }
        const int so = n * SSTR + kq * 16;
        *(short8*)(Sh + so)     = ph0;
        *(short8*)(Sh + so + 8) = ph1;
        *(short8*)(Sl + so)     = pl0;
        *(short8*)(Sl + so + 8) = pl1;
    }
    __syncthreads();   // S staged

    // ---- 4. resident S fragments: B[k=kb*32+q*8+j][n=(ns<<4)+l15]
    short8 shf[4][2], slf[4][2];
    #pragma unroll
    for (int ns = 0; ns < 4; ++ns)
        #pragma unroll
        for (int kb = 0; kb < 2; ++kb) {
            const int ro = ((ns << 4) + l15) * SSTR + kb * 32 + q * 8;
            shf[ns][kb] = *(const short8*)(Sh + ro);
            slf[ns][kb] = *(const short8*)(Sl + ro);
        }
    __syncthreads();   // frag reads done; Xs region now reusable for x tiles

    // ---- scatter LDS offsets are tile-invariant
    int lofs[12];
    #pragma unroll
    for (int p = 0; p < 12; ++p) {
        const int fid = p * 256 + tid;        // 0..3071
        const int b   = fid / 192;
        const int c4  = fid - b * 192;
        const int d0  = c4 * 4;
        const int i0  = d0 / 12;
        const int e0  = d0 - i0 * 12;         // in {0,4,8}
        lofs[p] = (b * NE + e0) * LSTR + i0;
    }

    // ---- scatter tile 0 to LDS transposed [(b,e)][i]
    #pragma unroll
    for (int p = 0; p < 12; ++p) {
        float* dst = Xs + lofs[p];
        dst[0 * LSTR] = v[p].x; dst[1 * LSTR] = v[p].y;
        dst[2 * LSTR] = v[p].z; dst[3 * LSTR] = v[p].w;
    }
    __syncthreads();   // B1: Xs ready for tile 0

    for (int tt = 0; tt < TPB; ++tt) {
        const int tile = tt * GRID + blockIdx.x;

        // ---- issue next tile's loads NOW (in flight during whole compute)
        if (tt + 1 < TPB) {
            const int ntile = (tt + 1) * GRID + blockIdx.x;
            const float4v* xg = (const float4v*)(x + (size_t)ntile * MB * (NF * NE));
            #pragma unroll
            for (int p = 0; p < 12; ++p) v[p] = xg[p * 256 + tid];
        }

        // ---- compute: 3 m-subtiles per wave, fused epilogue each
        #pragma unroll
        for (int ms = 0; ms < 3; ++ms) {
            const int msg  = w * 3 + ms;           // global m-subtile 0..11
            const int mrow = (msg << 4) + l15;     // A row: m = lane&15

            short8 ah[2], al[2];
            #pragma unroll
            for (int kb = 0; kb < 2; ++kb) {
                const float4v t0 = *(const float4v*)(Xs + mrow * LSTR + kb * 32 + q * 8);
                const float4v t1 = *(const float4v*)(Xs + mrow * LSTR + kb * 32 + q * 8 + 4);
                const float a8[8] = {t0.x, t0.y, t0.z, t0.w, t1.x, t1.y, t1.z, t1.w};
                #pragma unroll
                for (int j = 0; j < 8; ++j) {
                    const float vv = a8[j];
                    const __hip_bfloat16 h = __float2bfloat16(vv);
                    ah[kb][j] = bfb(vv);
                    al[kb][j] = bfb(vv - __bfloat162float(h));
                }
            }

            // acc init = linear-term fold: acc[ns][rg] = W[n*12 + e],
            // e = 4*((ms+q)%3) + rg  -> one ds_read_b128 per ns
            const int c0 = ((ms + q) % 3) * 4;
            float4v acc[4];
            #pragma unroll
            for (int ns = 0; ns < 4; ++ns)
                acc[ns] = *(const float4v*)(Wl + ((ns << 4) + l15) * 12 + c0);

            #pragma unroll
            for (int ns = 0; ns < 4; ++ns) {
                float4v c = acc[ns];
                c = __builtin_amdgcn_mfma_f32_16x16x32_bf16(ah[0], shf[ns][0], c, 0, 0, 0);
                c = __builtin_amdgcn_mfma_f32_16x16x32_bf16(ah[1], shf[ns][1], c, 0, 0, 0);
                c = __builtin_amdgcn_mfma_f32_16x16x32_bf16(al[0], shf[ns][0], c, 0, 0, 0);
                c = __builtin_amdgcn_mfma_f32_16x16x32_bf16(al[1], shf[ns][1], c, 0, 0, 0);
                c = __builtin_amdgcn_mfma_f32_16x16x32_bf16(ah[0], slf[ns][0], c, 0, 0, 0);
                c = __builtin_amdgcn_mfma_f32_16x16x32_bf16(ah[1], slf[ns][1], c, 0, 0, 0);
                acc[ns] = c;
            }

            // fused epilogue: P[m] = sum_n Xs_f32[m][n] * acc[m][n]
            // C/D: col n = l15, row m = q*4+rg
            #pragma unroll
            for (int rg = 0; rg < 4; ++rg) {
                const int m = (msg << 4) + (q << 2) + rg;
                float p = 0.0f;
                #pragma unroll
                for (int ns = 0; ns < 4; ++ns) {
                    const int n = (ns << 4) + l15;
                    p = fmaf(Xs[m * LSTR + n], acc[ns][rg], p);
                }
                p += __shfl_xor(p, 1);
                p += __shfl_xor(p, 2);
                p += __shfl_xor(p, 4);
                p += __shfl_xor(p, 8);
                if (l15 == 0) red[m] = p;
            }
        }
        __syncthreads();   // B2: red ready, Xs free for next scatter

        if (tid < MB) {
            float s = 0.0f;
            #pragma unroll
            for (int e = 0; e < NE; ++e) s += red[tid * NE + e];
            const float z = s + bias;
            out[tile * MB + tid] = 1.0f / (1.0f + __expf(-z));
        }

        // ---- scatter next tile (waits on its loads), then B1
        if (tt + 1 < TPB) {
            #pragma unroll
            for (int p = 0; p < 12; ++p) {
                float* dst = Xs + lofs[p];
                dst[0 * LSTR] = v[p].x; dst[1 * LSTR] = v[p].y;
                dst[2 * LSTR] = v[p].z; dst[3 * LSTR] = v[p].w;
            }
            __syncthreads();   // B1: Xs ready for tile tt+1
        }
    }
}

extern "C" void kernel_launch(void* const* d_in, const int* in_sizes, int n_in,
                              void* d_out, int out_size, void* d_ws, size_t ws_size,
                              hipStream_t stream) {
    const float* x  = (const float*)d_in[0];
    const float* W  = (const float*)d_in[1];  // [1,768]
    const float* bb = (const float*)d_in[2];  // [1]
    const float* V  = (const float*)d_in[3];  // [64,64,4]
    float* out = (float*)d_out;

    ffm_fused<<<dim3(GRID), dim3(256), 0, stream>>>(x, W, bb, V, out);
}

// Round 3
// 153.877 us; speedup vs baseline: 1.0499x; 1.0499x over previous
//
#include <hip/hip_runtime.h>
#include <hip/hip_bf16.h>

#define BATCH 32768
#define NF    64              // fields (K and N of the GEMM)
#define NE    12              // embedding dim
#define MB    16              // batch rows per tile
#define MROWS (MB*NE)         // 192 M-rows per tile
#define LSTR  68              // LDS f32 row stride (64 + 4 pad, b128-aligned)
#define NTILE (BATCH/MB)      // 2048
#define GRID  512
#define TPB   (NTILE/GRID)    // 4 tiles per block

typedef __attribute__((ext_vector_type(8))) short short8;   // 8 bf16 = 4 VGPR
typedef __attribute__((ext_vector_type(4))) float float4v;

// d_ws layout: ShT bf16[64][64] @0 (8KB) | SlT bf16[64][64] @8KB
#define WS_SHT 0
#define WS_SLT 8192

__device__ __forceinline__ short bfb(float v) {
    union { __hip_bfloat16 h; short s; } u;
    u.h = __float2bfloat16(v);
    return u.s;
}

// ---- prep: S = 0.5*<V[i,j],V[j,i]> (0 diag), split bf16 hi/lo, stored
// TRANSPOSED [n][k] for B-frag b128 loads.  (Separate tiny kernel: fusing
// this into ffm cost +6.5us in round 2 — 512x redundant work + prefetch drain.)
__global__ void prep_kernel(const float* __restrict__ V,
                            unsigned short* __restrict__ ShT,
                            unsigned short* __restrict__ SlT) {
    const int idx = blockIdx.x * 256 + threadIdx.x;
    if (idx < NF * NF) {
        const int i = idx >> 6, j = idx & 63;
        const float4v a = *(const float4v*)(V + (size_t)((i << 6) | j) * 4);
        const float4v b = *(const float4v*)(V + (size_t)((j << 6) | i) * 4);
        const float s = (i == j) ? 0.0f
                      : 0.5f * (a.x * b.x + a.y * b.y + a.z * b.z + a.w * b.w);
        const __hip_bfloat16 sh = __float2bfloat16(s);
        union { __hip_bfloat16 h; unsigned short u; } uh, ul;
        uh.h = sh; ul.h = __float2bfloat16(s - __bfloat162float(sh));
        ShT[(j << 6) | i] = uh.u;
        SlT[(j << 6) | i] = ul.u;
    }
}

// Wave-decomposed main kernel: wave w owns batch rows b in [4w, 4w+4) of each
// tile (m-rows [48w, 48w+48)).  Its x loads, LDS scatter, MFMA subtiles,
// reduction and output store are ALL wave-local -> no __syncthreads in the
// tile loop (one barrier total, for read-only Wl).  Waves skew freely,
// overlapping one wave's scatter/DS phase with another's MFMA/VALU phase.
__global__ __launch_bounds__(256, 2) void ffm_mfma(
    const float* __restrict__ x,
    const float* __restrict__ W,
    const float* __restrict__ bvec,
    const unsigned short* __restrict__ ShT,
    const unsigned short* __restrict__ SlT,
    float* __restrict__ out)
{
    __shared__ __align__(16) float Xs[MROWS * LSTR];   // 51 KB, [(b,e)][i] fp32
    __shared__ __align__(16) float red4[MROWS * 4];    // 3 KB, quad partials
    __shared__ __align__(16) float redP[MROWS];        // 768 B, per-m sums
    __shared__ float Wl[NF * NE];                      // 3 KB, W verbatim

    const int tid  = threadIdx.x;
    const int w    = tid >> 6;
    const int lane = tid & 63;
    const int l15  = lane & 15;
    const int q    = lane >> 4;

    // ---- wave-local prefetch of tile 0 quarter (issued first: HBM latency
    //      overlaps the S-frag / Wl staging below)
    float4v v[12];
    {
        const float4v* xg = (const float4v*)x;
        const size_t base = (size_t)blockIdx.x * 3072 + w * 768 + lane;
        #pragma unroll
        for (int p = 0; p < 12; ++p) v[p] = xg[base + p * 64];
    }

    const float bias = bvec[0];

    // ---- resident S fragments: B[k=kb*32+q*8+j][n=(ns<<4)+l15] (L2/L3-hot)
    short8 shf[4][2], slf[4][2];
    #pragma unroll
    for (int ns = 0; ns < 4; ++ns)
        #pragma unroll
        for (int kb = 0; kb < 2; ++kb) {
            const int off = ((ns << 4) + l15) * 64 + kb * 32 + q * 8;
            shf[ns][kb] = *(const short8*)(ShT + off);
            slf[ns][kb] = *(const short8*)(SlT + off);
        }

    // ---- stage W into LDS (read-only after the single barrier)
    #pragma unroll
    for (int k = 0; k < 3; ++k) Wl[k * 256 + tid] = W[k * 256 + tid];
    __syncthreads();   // the ONLY barrier

    // ---- wave-local scatter offsets (tile-invariant)
    int lofs[12];
    #pragma unroll
    for (int p = 0; p < 12; ++p) {
        const int f0   = p * 256 + lane * 4;    // quarter-local float idx
        const int brow = f0 / 768;              // 0..3
        const int r    = f0 - brow * 768;
        const int i0   = r / 12;
        const int e0   = r - i0 * 12;           // in {0,4,8}, never wraps
        const int m    = (4 * w + brow) * NE + e0;
        lofs[p] = m * LSTR + i0;
    }

    for (int tt = 0; tt < TPB; ++tt) {
        const int tile = tt * GRID + blockIdx.x;

        // ---- scatter own quarter to LDS transposed [(b,e)][i]
        //      (4 rows, same col -> compiler fuses into ds_write2_b32 pairs)
        #pragma unroll
        for (int p = 0; p < 12; ++p) {
            float* dst = Xs + lofs[p];
            dst[0 * LSTR] = v[p].x; dst[1 * LSTR] = v[p].y;
            dst[2 * LSTR] = v[p].z; dst[3 * LSTR] = v[p].w;
        }

        // ---- issue next tile's quarter NOW (in flight during whole compute)
        if (tt + 1 < TPB) {
            const int ntile = (tt + 1) * GRID + blockIdx.x;
            const float4v* xg = (const float4v*)x;
            const size_t base = (size_t)ntile * 3072 + w * 768 + lane;
            #pragma unroll
            for (int p = 0; p < 12; ++p) v[p] = xg[base + p * 64];
        }

        // ---- compute: 3 m-subtiles, all rows wave-local
        #pragma unroll
        for (int ms = 0; ms < 3; ++ms) {
            const int msg  = w * 3 + ms;           // global m-subtile 0..11
            const int mrow = (msg << 4) + l15;     // A row: m = lane&15

            short8 ah[2], al[2];
            #pragma unroll
            for (int kb = 0; kb < 2; ++kb) {
                const float4v t0 = *(const float4v*)(Xs + mrow * LSTR + kb * 32 + q * 8);
                const float4v t1 = *(const float4v*)(Xs + mrow * LSTR + kb * 32 + q * 8 + 4);
                const float a8[8] = {t0.x, t0.y, t0.z, t0.w, t1.x, t1.y, t1.z, t1.w};
                #pragma unroll
                for (int j = 0; j < 8; ++j) {
                    const float vv = a8[j];
                    const __hip_bfloat16 h = __float2bfloat16(vv);
                    ah[kb][j] = bfb(vv);
                    al[kb][j] = bfb(vv - __bfloat162float(h));
                }
            }

            // acc init = linear-term fold: one ds_read_b128 per ns
            const int c0 = ((ms + q) % 3) * 4;
            float4v acc[4];
            #pragma unroll
            for (int ns = 0; ns < 4; ++ns)
                acc[ns] = *(const float4v*)(Wl + ((ns << 4) + l15) * 12 + c0);

            #pragma unroll
            for (int ns = 0; ns < 4; ++ns) {
                float4v c = acc[ns];
                c = __builtin_amdgcn_mfma_f32_16x16x32_bf16(ah[0], shf[ns][0], c, 0, 0, 0);
                c = __builtin_amdgcn_mfma_f32_16x16x32_bf16(ah[1], shf[ns][1], c, 0, 0, 0);
                c = __builtin_amdgcn_mfma_f32_16x16x32_bf16(al[0], shf[ns][0], c, 0, 0, 0);
                c = __builtin_amdgcn_mfma_f32_16x16x32_bf16(al[1], shf[ns][1], c, 0, 0, 0);
                c = __builtin_amdgcn_mfma_f32_16x16x32_bf16(ah[0], slf[ns][0], c, 0, 0, 0);
                c = __builtin_amdgcn_mfma_f32_16x16x32_bf16(ah[1], slf[ns][1], c, 0, 0, 0);
                acc[ns] = c;
            }

            // fused epilogue: P[m] = sum_n Xs_f32[m][n] * acc[m][n]
            // 2-level shfl (quad sums) + quad-partial LDS write: halves the
            // shfl count vs a full 4-level tree.
            #pragma unroll
            for (int rg = 0; rg < 4; ++rg) {
                const int m = (msg << 4) + (q << 2) + rg;
                float p = 0.0f;
                #pragma unroll
                for (int ns = 0; ns < 4; ++ns) {
                    const int n = (ns << 4) + l15;
                    p = fmaf(Xs[m * LSTR + n], acc[ns][rg], p);
                }
                p += __shfl_xor(p, 1);
                p += __shfl_xor(p, 2);
                if ((l15 & 3) == 0) red4[m * 4 + (l15 >> 2)] = p;
            }
        }

        // ---- wave-local tail: sum quads -> P[m]; sum e -> logits; store
        {
            float pm = 0.0f;
            if (lane < 48) {
                const float4v r4 = *(const float4v*)(red4 + (48 * w + lane) * 4);
                pm = r4.x + r4.y + r4.z + r4.w;
                redP[48 * w + lane] = pm;
            }
            if (lane < 4) {
                const float* rp = redP + 48 * w + lane * 12;
                const float4v a = *(const float4v*)(rp);
                const float4v b = *(const float4v*)(rp + 4);
                const float4v c = *(const float4v*)(rp + 8);
                const float s = (a.x + a.y + a.z + a.w)
                              + (b.x + b.y + b.z + b.w)
                              + (c.x + c.y + c.z + c.w) + bias;
                out[tile * MB + w * 4 + lane] = 1.0f / (1.0f + __expf(-s));
            }
        }
        // no barrier: next scatter touches only this wave's own rows
    }
}

extern "C" void kernel_launch(void* const* d_in, const int* in_sizes, int n_in,
                              void* d_out, int out_size, void* d_ws, size_t ws_size,
                              hipStream_t stream) {
    const float* x  = (const float*)d_in[0];
    const float* W  = (const float*)d_in[1];  // [1,768]
    const float* bb = (const float*)d_in[2];  // [1]
    const float* V  = (const float*)d_in[3];  // [64,64,4]
    unsigned short* ShT = (unsigned short*)((char*)d_ws + WS_SHT);
    unsigned short* SlT = (unsigned short*)((char*)d_ws + WS_SLT);
    float* out = (float*)d_out;

    prep_kernel<<<dim3(16), dim3(256), 0, stream>>>(V, ShT, SlT);
    ffm_mfma<<<dim3(GRID), dim3(256), 0, stream>>>(x, W, bb, ShT, SlT, out);
}